// Round 11
// baseline (436.353 us; speedup 1.0000x reference)
//
#include <hip/hip_runtime.h>
#include <hip/hip_bf16.h>

#define N_NODES 8192
#define EMB 256
#define NHID 64
#define LOG2E 1.44269504088896340736f
#define S_SPLIT 32
#define COLS 256       // cols per k2 block = N_NODES / S_SPLIT
#define NKT 8          // K-tiles per block = COLS / 32
#define HROW 264       // padded LDS row stride (shorts) for hT tile
#define MROW 40        // padded LDS row stride (bytes) for mask tile (8B-aligned)
#define PACK_BLOCKS 8192  // (N*N/32) chunks / 256 threads = 2097152/256
#define K1_BLOCKS 2048    // N_NODES / 4

typedef __attribute__((ext_vector_type(8))) short bf16x8;
typedef __attribute__((ext_vector_type(4))) float f32x4;

static __device__ __forceinline__ short f2bf(float f) {
  __hip_bfloat16 h = __float2bfloat16(f);  // round-to-nearest-even
  return *reinterpret_cast<short*>(&h);
}

// fast bf16 round (half-up in magnitude) — used on nonnegative attention
// weights where ties-away vs ties-even rounding is noise.
static __device__ __forceinline__ short f2bf_fast(float f) {
  unsigned u = __builtin_bit_cast(unsigned, f);
  return (short)((u + 0x8000u) >> 16);
}

// Fused kernel 0+1.
//  blocks [0, PACK_BLOCKS): adj -> bitmask. STREAM-SHAPED: each block reads
//    32 KB contiguous (each thread 128 B contiguous); pages opened once and
//    fully consumed. Bit i of dword c = adj[c*32+i] != 0.
//  blocks [PACK_BLOCKS, +K1_BLOCKS): h = input @ W (one wave per row),
//    writes hT[d][row] bf16 + log2e-scaled s_src/s_dst.
__global__ __launch_bounds__(256) void gat_k01(
    const int* __restrict__ adj, unsigned* __restrict__ mask32,
    const float* __restrict__ in, const float* __restrict__ W,
    const float* __restrict__ a, short* __restrict__ hT,
    float* __restrict__ ssrc, float* __restrict__ sdst) {
  if (blockIdx.x < PACK_BLOCKS) {
    int c = blockIdx.x * 256 + threadIdx.x;  // chunk = 32 ints = 128 B
    const int4* p = reinterpret_cast<const int4*>(adj) + (size_t)c * 8;
    unsigned m = 0;
#pragma unroll
    for (int j = 0; j < 8; ++j) {
      int4 v = p[j];
      m |= (unsigned)(v.x != 0) << (j * 4 + 0);
      m |= (unsigned)(v.y != 0) << (j * 4 + 1);
      m |= (unsigned)(v.z != 0) << (j * 4 + 2);
      m |= (unsigned)(v.w != 0) << (j * 4 + 3);
    }
    mask32[c] = m;
    return;
  }
  int wv = threadIdx.x >> 6, lane = threadIdx.x & 63;
  int row = (blockIdx.x - PACK_BLOCKS) * 4 + wv;
  int d = lane;
  const float4* in4 = reinterpret_cast<const float4*>(in + (size_t)row * EMB);
  float acc = 0.f;
#pragma unroll 4
  for (int k4 = 0; k4 < EMB / 4; ++k4) {
    float4 x = in4[k4];
    int k = k4 * 4;
    acc = fmaf(x.x, W[(k + 0) * NHID + d], acc);
    acc = fmaf(x.y, W[(k + 1) * NHID + d], acc);
    acc = fmaf(x.z, W[(k + 2) * NHID + d], acc);
    acc = fmaf(x.w, W[(k + 3) * NHID + d], acc);
  }
  hT[(size_t)d * N_NODES + row] = f2bf(acc);
  float p1 = acc * a[d];
  float p2 = acc * a[NHID + d];
#pragma unroll
  for (int off = 32; off > 0; off >>= 1) {
    p1 += __shfl_xor(p1, off);
    p2 += __shfl_xor(p2, off);
  }
  if (lane == 0) {
    ssrc[row] = p1 * LOG2E;
    sdst[row] = p2 * LOG2E;
  }
}

// Kernel 2: fused masked-exp + P@h via bf16 MFMA (R8's k2 — stage phase is
// all cache-resident: 2 KB mask (L3-warm) + 33 KB hT (L2) + 1 KB sdst).
// The K-loop touches no global memory.
__global__ __launch_bounds__(256, 4) void gat_k2(
    const unsigned char* __restrict__ maskb, const short* __restrict__ hT,
    const float* __restrict__ ssrc, const float* __restrict__ sdst,
    float* __restrict__ pacc, float* __restrict__ pz) {
  __shared__ short hlds[64 * HROW];                                  // 33792 B
  __shared__ unsigned char mlds[64 * MROW] __attribute__((aligned(8)));  // 2560 B
  __shared__ float tlds[COLS];                                       // 1024 B

  int split = blockIdx.x >> 7;
  int rb = blockIdx.x & 127;
  int tid = threadIdx.x;
  int c0 = split * COLS;
  int wv = tid >> 6, lane = tid & 63;

  // ---- stage hT slice: 64 dims x 512 B ----
#pragma unroll
  for (int p = 0; p < 8; ++p) {
    int flat = p * 4096 + tid * 16;    // byte offset within [64][512B]
    int srow = flat >> 9;              // dim
    int scol = (flat & 511) >> 1;      // short index within row
    bf16x8 v = *reinterpret_cast<const bf16x8*>(
        hT + (size_t)srow * N_NODES + c0 + scol);
    *reinterpret_cast<bf16x8*>(&hlds[srow * HROW + scol]) = v;
  }
  if (tid < 64) {
    float4 t4 = *reinterpret_cast<const float4*>(sdst + c0 + tid * 4);
    *reinterpret_cast<float4*>(&tlds[tid * 4]) = t4;
  }
  // ---- stage mask tile: 64 rows x 32 B (8 B per thread) ----
  {
    int r = tid >> 2, k = tid & 3;
    unsigned long long m = *reinterpret_cast<const unsigned long long*>(
        maskb + (size_t)(rb * 64 + r) * (N_NODES / 8) + split * 32 + k * 8);
    *reinterpret_cast<unsigned long long*>(&mlds[r * MROW + k * 8]) = m;
  }
  __syncthreads();

  int lrow = lane & 15, kg = lane >> 4;
  int r0 = rb * 64 + wv * 16;
  float s_i = ssrc[r0 + lrow];

  f32x4 acc0 = {0.f, 0.f, 0.f, 0.f};
  f32x4 acc1 = acc0, acc2 = acc0, acc3 = acc0;
  float zacc = 0.f;

#pragma unroll
  for (int kt = 0; kt < NKT; ++kt) {
    int cb = kt * 32 + kg * 8;
    // block-local mask row; 16 distinct banks across lrow, kg within-dword
    unsigned mb = mlds[(wv * 16 + lrow) * MROW + kt * 4 + kg];
    float4 tA = *reinterpret_cast<const float4*>(&tlds[cb]);
    float4 tB = *reinterpret_cast<const float4*>(&tlds[cb + 4]);
    bf16x8 b0 = *reinterpret_cast<const bf16x8*>(&hlds[(lrow + 0) * HROW + cb]);
    bf16x8 b1 = *reinterpret_cast<const bf16x8*>(&hlds[(lrow + 16) * HROW + cb]);
    bf16x8 b2 = *reinterpret_cast<const bf16x8*>(&hlds[(lrow + 32) * HROW + cb]);
    bf16x8 b3 = *reinterpret_cast<const bf16x8*>(&hlds[(lrow + 48) * HROW + cb]);

    float tv[8] = {tA.x, tA.y, tA.z, tA.w, tB.x, tB.y, tB.z, tB.w};
    bf16x8 af;
#pragma unroll
    for (int e = 0; e < 8; ++e) {
      float x = s_i + tv[e];                   // log2-domain score
      float lk = fmaxf(x, 0.2f * x);           // leakyrelu (alpha<1)
      float ev = __builtin_amdgcn_exp2f(lk);   // exp(leaky(s+t))
      float w = (mb & (1u << e)) ? ev : 0.f;   // mask
      zacc += w;
      af[e] = f2bf_fast(w);
    }
    acc0 = __builtin_amdgcn_mfma_f32_16x16x32_bf16(af, b0, acc0, 0, 0, 0);
    acc1 = __builtin_amdgcn_mfma_f32_16x16x32_bf16(af, b1, acc1, 0, 0, 0);
    acc2 = __builtin_amdgcn_mfma_f32_16x16x32_bf16(af, b2, acc2, 0, 0, 0);
    acc3 = __builtin_amdgcn_mfma_f32_16x16x32_bf16(af, b3, acc3, 0, 0, 0);
  }

  // Z: A-layout row = lane&15; sum over lanes {r, r+16, r+32, r+48}
  float z = zacc;
  z += __shfl_xor(z, 16);
  z += __shfl_xor(z, 32);
  if (lane < 16) pz[(size_t)split * N_NODES + r0 + lane] = z;

  // C/D layout: row = (lane>>4)*4 + reg, col = lane&15
  float* pa = pacc + (size_t)split * (N_NODES * NHID);
#pragma unroll
  for (int reg = 0; reg < 4; ++reg) {
    int orow = r0 + kg * 4 + reg;
    pa[(size_t)orow * NHID + 0 * 16 + lrow] = acc0[reg];
    pa[(size_t)orow * NHID + 1 * 16 + lrow] = acc1[reg];
    pa[(size_t)orow * NHID + 2 * 16 + lrow] = acc2[reg];
    pa[(size_t)orow * NHID + 3 * 16 + lrow] = acc3[reg];
  }
}

// Kernel 3: combine split partials and normalize (float4 per thread).
__global__ __launch_bounds__(256) void gat_k3(
    const float* __restrict__ pacc, const float* __restrict__ pz,
    float* __restrict__ out) {
  int t = blockIdx.x * 256 + threadIdx.x;  // indexes float4
  int row = t >> 4;                        // 16 float4 per row (NHID=64)
  float4 num = {0.f, 0.f, 0.f, 0.f};
  float den = 0.f;
#pragma unroll 8
  for (int s = 0; s < S_SPLIT; ++s) {
    float4 p = *reinterpret_cast<const float4*>(
        &pacc[(size_t)s * (N_NODES * NHID) + (size_t)t * 4]);
    num.x += p.x; num.y += p.y; num.z += p.z; num.w += p.w;
    den += pz[(size_t)s * N_NODES + row];
  }
  float r = 1.f / den;
  float4 o = {num.x * r, num.y * r, num.z * r, num.w * r};
  *reinterpret_cast<float4*>(&out[(size_t)t * 4]) = o;
}

extern "C" void kernel_launch(void* const* d_in, const int* in_sizes, int n_in,
                              void* d_out, int out_size, void* d_ws, size_t ws_size,
                              hipStream_t stream) {
  (void)in_sizes; (void)n_in; (void)out_size; (void)ws_size;
  const float* in = (const float*)d_in[0];
  const int* adj = (const int*)d_in[1];
  const float* W = (const float*)d_in[2];
  const float* a = (const float*)d_in[3];
  float* out = (float*)d_out;

  // ws: hT (1 MB) | ssrc (32K) | sdst (32K) | pz (1 MB) | pacc (64 MB) | mask (8 MB)
  char* w = (char*)d_ws;
  short* hT = (short*)w;
  float* ssrc = (float*)(w + (1u << 20));
  float* sdst = ssrc + N_NODES;
  float* pz = sdst + N_NODES;
  float* pacc = pz + (size_t)S_SPLIT * N_NODES;
  unsigned* mask32 = (unsigned*)(pacc + (size_t)S_SPLIT * (N_NODES * NHID));

  gat_k01<<<PACK_BLOCKS + K1_BLOCKS, 256, 0, stream>>>(adj, mask32, in, W, a,
                                                       hT, ssrc, sdst);
  gat_k2<<<128 * S_SPLIT, 256, 0, stream>>>((const unsigned char*)mask32, hT,
                                            ssrc, sdst, pacc, pz);
  gat_k3<<<(N_NODES * NHID) / (256 * 4), 256, 0, stream>>>(pacc, pz, out);
}